// Round 2
// baseline (4240.851 us; speedup 1.0000x reference)
//
#include <hip/hip_runtime.h>
#include <math.h>

#define BB 512
#define LL 128
#define FD 8
#define HD 512
#define EPSV 1e-5f

__device__ __forceinline__ float silu_f(float x){ return x / (1.0f + expf(-x)); }
__device__ __forceinline__ float softplus_f(float x){ return (x > 20.0f) ? x : log1pf(expf(x)); }

// ---------------- embed: h = x @ w0 + b0 (rows = chunk rows) ----------------
__global__ __launch_bounds__(256) void k_embed(const float* __restrict__ x,
    const float* __restrict__ w0, const float* __restrict__ b0,
    float* __restrict__ h)
{
    int idx = blockIdx.x*256 + threadIdx.x;      // over rows*HD
    int c = idx & (HD-1);
    int row = idx >> 9;
    const float* xr = x + (size_t)row*FD;
    float acc = b0[c];
    #pragma unroll
    for (int f=0; f<FD; ++f) acc = fmaf(xr[f], w0[f*HD + c], acc);
    h[idx] = acc;
}

// ---------------- tiled fp32 GEMM, 128x128 tile, 8x8 microtile ----------------
// MODE 0: C = A0(rowsx512) @ W(512x1024) + bias; col<512 -> out0=silu(v) (z), else out1=v (xi)
// MODE 1: C = [A0|A1](rowsx1024) @ W(1024x512) + bias + resid -> out0
template<int KT, int MODE>
__global__ __launch_bounds__(256) void k_gemm(
    const float* __restrict__ A0, const float* __restrict__ A1,
    const float* __restrict__ W, const float* __restrict__ bias,
    const float* __restrict__ resid, float* __restrict__ out0,
    float* __restrict__ out1, int N)
{
    __shared__ float As[32][132];   // [k][m], padded
    __shared__ float Bs[32][128];   // [k][n]
    const int tid = threadIdx.x;
    const int tx = tid & 15, ty = tid >> 4;
    const int rowBase = blockIdx.y * 128;
    const int nBase   = blockIdx.x * 128;
    float acc[8][8] = {};

    for (int kt = 0; kt < KT; ++kt) {
        const int k0 = kt * 32;
        const float* Ap = (MODE == 1 && k0 >= 512) ? (A1 + (k0 - 512)) : (A0 + k0);
        #pragma unroll
        for (int i = 0; i < 4; ++i) {        // A tile 128x32, transpose into LDS
            int q = tid + i*256;
            int r = q >> 3, kq = (q & 7) * 4;
            float4 v = *(const float4*)(Ap + (size_t)(rowBase + r)*512 + kq);
            As[kq+0][r] = v.x; As[kq+1][r] = v.y; As[kq+2][r] = v.z; As[kq+3][r] = v.w;
        }
        #pragma unroll
        for (int i = 0; i < 4; ++i) {        // W tile 32x128
            int q = tid + i*256;
            int kr = q >> 5, nq = (q & 31) * 4;
            *(float4*)&Bs[kr][nq] = *(const float4*)(W + (size_t)(k0 + kr)*N + nBase + nq);
        }
        __syncthreads();
        #pragma unroll
        for (int k = 0; k < 32; ++k) {
            float a[8], b[8];
            *(float4*)&a[0] = *(const float4*)&As[k][ty*8];
            *(float4*)&a[4] = *(const float4*)&As[k][ty*8+4];
            *(float4*)&b[0] = *(const float4*)&Bs[k][tx*8];
            *(float4*)&b[4] = *(const float4*)&Bs[k][tx*8+4];
            #pragma unroll
            for (int i = 0; i < 8; ++i)
                #pragma unroll
                for (int j = 0; j < 8; ++j)
                    acc[i][j] = fmaf(a[i], b[j], acc[i][j]);
        }
        __syncthreads();
    }

    #pragma unroll
    for (int i = 0; i < 8; ++i) {
        int row = rowBase + ty*8 + i;
        size_t rb = (size_t)row * 512;
        #pragma unroll
        for (int j4 = 0; j4 < 2; ++j4) {
            int col = nBase + tx*8 + j4*4;
            float v0 = acc[i][j4*4+0] + bias[col+0];
            float v1 = acc[i][j4*4+1] + bias[col+1];
            float v2 = acc[i][j4*4+2] + bias[col+2];
            float v3 = acc[i][j4*4+3] + bias[col+3];
            if (MODE == 0) {
                if (col < 512) {
                    float4 o; o.x = silu_f(v0); o.y = silu_f(v1); o.z = silu_f(v2); o.w = silu_f(v3);
                    *(float4*)(out0 + rb + col) = o;
                } else {
                    float4 o; o.x = v0; o.y = v1; o.z = v2; o.w = v3;
                    *(float4*)(out1 + rb + col - 512) = o;
                }
            } else {
                float4 r4 = *(const float4*)(resid + rb + col);
                float4 o; o.x = v0 + r4.x; o.y = v1 + r4.y; o.z = v2 + r4.z; o.w = v3 + r4.w;
                *(float4*)(out0 + rb + col) = o;
            }
        }
    }
}

// ---------------- depthwise conv3 (pad 1) + bias + silu ----------------
__global__ __launch_bounds__(256) void k_conv(const float* __restrict__ xi,
    const float* __restrict__ cw, const float* __restrict__ cb,
    float* __restrict__ outc)
{
    int idx = blockIdx.x*256 + threadIdx.x;   // over rows*HD, rows multiple of 128
    int c = idx & (HD-1);
    int l = (idx >> 9) & (LL-1);
    float xm = (l > 0)     ? xi[idx - HD] : 0.0f;
    float x0 = xi[idx];
    float xp = (l < LL-1)  ? xi[idx + HD] : 0.0f;
    float v = cb[c];
    v = fmaf(xm, cw[c*3+0], v);
    v = fmaf(x0, cw[c*3+1], v);
    v = fmaf(xp, cw[c*3+2], v);
    outc[idx] = silu_f(v);
}

// ---------------- dt bottleneck: xc *= softplus((xc@xp_w+xp_b)@dt_w+dt_b), per row ----------------
__global__ __launch_bounds__(256) void k_dt(float* __restrict__ xc,
    const float* __restrict__ xp_w, const float* __restrict__ xp_b,
    const float* __restrict__ dt_w, const float* __restrict__ dt_b)
{
    __shared__ float sj[4][16];
    __shared__ float tj[16];
    int row = blockIdx.x, tid = threadIdx.x;
    size_t base = (size_t)row * HD;
    float x0 = xc[base + tid];
    float x1 = xc[base + tid + 256];
    float tp[16];
    #pragma unroll
    for (int j = 0; j < 16; ++j)
        tp[j] = x0 * xp_w[tid*16 + j] + x1 * xp_w[(tid+256)*16 + j];
    #pragma unroll
    for (int j = 0; j < 16; ++j) {
        float v = tp[j];
        for (int off = 32; off; off >>= 1) v += __shfl_down(v, off);
        tp[j] = v;
    }
    int lane = tid & 63, wid = tid >> 6;
    if (lane == 0) {
        #pragma unroll
        for (int j = 0; j < 16; ++j) sj[wid][j] = tp[j];
    }
    __syncthreads();
    if (tid < 16) tj[tid] = sj[0][tid] + sj[1][tid] + sj[2][tid] + sj[3][tid] + xp_b[tid];
    __syncthreads();
    float d0 = dt_b[tid], d1 = dt_b[tid + 256];
    #pragma unroll
    for (int j = 0; j < 16; ++j) {
        float t = tj[j];
        d0 = fmaf(t, dt_w[j*HD + tid],       d0);
        d1 = fmaf(t, dt_w[j*HD + tid + 256], d1);
    }
    xc[base + tid]       = x0 * softplus_f(d0);
    xc[base + tid + 256] = x1 * softplus_f(d1);
}

// ---------------- layernorm over last dim (512) ----------------
__global__ __launch_bounds__(256) void k_ln(const float* __restrict__ in,
    const float* __restrict__ g, const float* __restrict__ b,
    float* __restrict__ out)
{
    __shared__ float s1[4], s2[4], sm[2];
    int row = blockIdx.x, tid = threadIdx.x;
    size_t base = (size_t)row * HD;
    float x0 = in[base + tid], x1 = in[base + tid + 256];
    float s = x0 + x1, q = x0*x0 + x1*x1;
    for (int off = 32; off; off >>= 1) { s += __shfl_down(s, off); q += __shfl_down(q, off); }
    int lane = tid & 63, wid = tid >> 6;
    if (!lane) { s1[wid] = s; s2[wid] = q; }
    __syncthreads();
    if (!tid) {
        float ts = s1[0]+s1[1]+s1[2]+s1[3];
        float tq = s2[0]+s2[1]+s2[2]+s2[3];
        float mu = ts / (float)HD;
        float var = tq / (float)HD - mu*mu;
        sm[0] = mu; sm[1] = rsqrtf(var + EPSV);
    }
    __syncthreads();
    float mu = sm[0], rs = sm[1];
    out[base + tid]       = (x0 - mu) * rs * g[tid]       + b[tid];
    out[base + tid + 256] = (x1 - mu) * rs * g[tid + 256] + b[tid + 256];
}

// ---------------- head: reg/dec, gate softmax+argmax, expert select ----------------
__global__ __launch_bounds__(256) void k_head(const float* __restrict__ h,
    const float* __restrict__ gumbel, const float* __restrict__ gate_w,
    const float* __restrict__ gate_b, const float* __restrict__ actor_w,
    const float* __restrict__ actor_b, const float* __restrict__ critic_w,
    const float* __restrict__ critic_b, float* __restrict__ out, int bofs)
{
    __shared__ float sred[4][4];
    __shared__ float sg;
    __shared__ int sestar;
    int bl = blockIdx.x, tid = threadIdx.x;
    int b = bofs + bl;                     // absolute batch index
    size_t base = (size_t)bl * LL * HD;
    float r0 = 0.f, r1 = 0.f;
    for (int l = 0; l < LL; ++l) {
        r0 += h[base + l*HD + tid];
        r1 += h[base + l*HD + tid + 256];
    }
    r0 *= (1.0f/LL); r1 *= (1.0f/LL);
    float dec0 = h[base + (LL-1)*HD + tid];
    float dec1 = h[base + (LL-1)*HD + tid + 256];

    float p[4];
    #pragma unroll
    for (int e = 0; e < 4; ++e)
        p[e] = r0 * gate_w[tid*4 + e] + r1 * gate_w[(tid+256)*4 + e];
    #pragma unroll
    for (int e = 0; e < 4; ++e) {
        float v = p[e];
        for (int off = 32; off; off >>= 1) v += __shfl_down(v, off);
        p[e] = v;
    }
    int lane = tid & 63, wid = tid >> 6;
    if (!lane) { for (int e = 0; e < 4; ++e) sred[wid][e] = p[e]; }
    __syncthreads();
    if (!tid) {
        float ge[4]; float mx = -1e30f;
        for (int e = 0; e < 4; ++e) {
            ge[e] = sred[0][e]+sred[1][e]+sred[2][e]+sred[3][e] + gate_b[e] + gumbel[b*4 + e];
            if (ge[e] > mx) mx = ge[e];
        }
        float ys[4], den = 0.f;
        for (int e = 0; e < 4; ++e) { ys[e] = expf(ge[e] - mx); den += ys[e]; }
        int estar = 0; float best = ge[0];
        for (int e = 1; e < 4; ++e) if (ge[e] > best) { best = ge[e]; estar = e; }
        float ye = ys[estar] / den;
        float gv = (1.0f + ye) - ye;          // exactly as reference: (hard + y) - y
        for (int e = 0; e < 4; ++e) out[2048 + b*4 + e] = (e == estar) ? gv : 0.0f;
        sg = gv; sestar = estar;
    }
    __syncthreads();
    float gv = sg; int estar = sestar;
    const float* aw  = actor_w  + (size_t)estar * HD * 3;
    const float* cwp = critic_w + (size_t)estar * HD;
    float q[4];
    #pragma unroll
    for (int a = 0; a < 3; ++a)
        q[a] = dec0 * aw[tid*3 + a] + dec1 * aw[(tid+256)*3 + a];
    q[3] = dec0 * cwp[tid] + dec1 * cwp[tid + 256];
    #pragma unroll
    for (int e = 0; e < 4; ++e) {
        float v = q[e];
        for (int off = 32; off; off >>= 1) v += __shfl_down(v, off);
        q[e] = v;
    }
    __syncthreads();
    if (!lane) { for (int e = 0; e < 4; ++e) sred[wid][e] = q[e]; }
    __syncthreads();
    if (!tid) {
        for (int a = 0; a < 3; ++a) {
            float v = sred[0][a]+sred[1][a]+sred[2][a]+sred[3][a];
            out[b*3 + a] = gv * (v + actor_b[estar*3 + a]);
        }
        float v = sred[0][3]+sred[1][3]+sred[2][3]+sred[3][3];
        out[1536 + b] = gv * (v + critic_b[estar]);
    }
}

extern "C" void kernel_launch(void* const* d_in, const int* in_sizes, int n_in,
                              void* d_out, int out_size, void* d_ws, size_t ws_size,
                              hipStream_t stream)
{
    const float* x        = (const float*)d_in[0];
    const float* gumbel   = (const float*)d_in[1];
    const float* w0       = (const float*)d_in[2];
    const float* b0       = (const float*)d_in[3];
    const float* ln_g     = (const float*)d_in[4];
    const float* ln_b     = (const float*)d_in[5];
    const float* gate_w   = (const float*)d_in[6];
    const float* gate_b   = (const float*)d_in[7];
    const float* actor_w  = (const float*)d_in[8];
    const float* actor_b  = (const float*)d_in[9];
    const float* critic_w = (const float*)d_in[10];
    const float* critic_b = (const float*)d_in[11];
    const float* in_w[2]   = {(const float*)d_in[12], (const float*)d_in[22]};
    const float* in_b[2]   = {(const float*)d_in[13], (const float*)d_in[23]};
    const float* conv_w[2] = {(const float*)d_in[14], (const float*)d_in[24]};
    const float* conv_b[2] = {(const float*)d_in[15], (const float*)d_in[25]};
    const float* xp_w[2]   = {(const float*)d_in[16], (const float*)d_in[26]};
    const float* xp_b[2]   = {(const float*)d_in[17], (const float*)d_in[27]};
    const float* dt_w[2]   = {(const float*)d_in[18], (const float*)d_in[28]};
    const float* dt_b[2]   = {(const float*)d_in[19], (const float*)d_in[29]};
    const float* out_w[2]  = {(const float*)d_in[20], (const float*)d_in[30]};
    const float* out_b[2]  = {(const float*)d_in[21], (const float*)d_in[31]};

    // Chunk the batch dimension so 4 activation buffers fit in ws_size.
    // CB = batches per chunk (power-of-two divisor of 512).
    int CB = 512;
    while (CB > 1 && (size_t)4 * CB * LL * HD * sizeof(float) > ws_size) CB >>= 1;
    const int rows = CB * LL;                    // rows per chunk
    const size_t CSZ = (size_t)rows * HD;        // floats per buffer

    float* ws  = (float*)d_ws;
    float* h   = ws;                             // hidden state (chunk)
    float* z   = ws + CSZ;                       // silu(z) half of in_proj
    float* xb  = ws + 2*CSZ;                     // xi half; reused as gemm1 out
    float* cbf = ws + 3*CSZ;                     // conv out / xi*dt

    const int nchunk = BB / CB;
    for (int c = 0; c < nchunk; ++c) {
        const float* xin = x + (size_t)c * CB * LL * FD;
        k_embed<<<rows*HD/256, 256, 0, stream>>>(xin, w0, b0, h);
        for (int m = 0; m < 2; ++m) {
            k_gemm<16,0><<<dim3(8, CB), 256, 0, stream>>>(h, nullptr, in_w[m], in_b[m], nullptr, z, xb, 1024);
            k_conv<<<rows*HD/256, 256, 0, stream>>>(xb, conv_w[m], conv_b[m], cbf);
            k_dt<<<rows, 256, 0, stream>>>(cbf, xp_w[m], xp_b[m], dt_w[m], dt_b[m]);
            k_gemm<32,1><<<dim3(4, CB), 256, 0, stream>>>(cbf, z, out_w[m], out_b[m], h, xb, nullptr, 512);
            k_ln<<<rows, 256, 0, stream>>>(xb, ln_g, ln_b, h);
        }
        k_head<<<CB, 256, 0, stream>>>(h, gumbel, gate_w, gate_b, actor_w, actor_b,
                                       critic_w, critic_b, (float*)d_out, c*CB);
    }
}

// Round 3
// 2328.332 us; speedup vs baseline: 1.8214x; 1.8214x over previous
//
#include <hip/hip_runtime.h>
#include <math.h>

#define BB 512
#define LL 128
#define FD 8
#define HD 512
#define EPSV 1e-5f

typedef __attribute__((ext_vector_type(8))) __bf16 bf16x8;
typedef __attribute__((ext_vector_type(4))) float floatx4;

__device__ __forceinline__ float silu_f(float x){ return x / (1.0f + expf(-x)); }
__device__ __forceinline__ float softplus_f(float x){ return (x > 20.0f) ? x : log1pf(expf(x)); }

__device__ __forceinline__ unsigned short f2bf(float x){
    union { float f; unsigned u; } v; v.f = x;
    unsigned r = v.u + 0x7fffu + ((v.u >> 16) & 1u);   // RNE
    return (unsigned short)(r >> 16);
}
__device__ __forceinline__ float bf2f(unsigned short h){
    union { unsigned u; float f; } v; v.u = ((unsigned)h) << 16; return v.f;
}
__device__ __forceinline__ void split_bf(float x, unsigned short* hi, unsigned short* lo){
    unsigned short h = f2bf(x);
    *hi = h;
    *lo = f2bf(x - bf2f(h));
}

// ---------------- embed: h = x @ w0 + b0; also emit h_hi/h_lo bf16 ----------------
__global__ __launch_bounds__(256) void k_embed(const float* __restrict__ x,
    const float* __restrict__ w0, const float* __restrict__ b0,
    float* __restrict__ h, unsigned short* __restrict__ hhi, unsigned short* __restrict__ hlo)
{
    int idx = blockIdx.x*256 + threadIdx.x;      // over rows*HD
    int c = idx & (HD-1);
    int row = idx >> 9;
    const float* xr = x + (size_t)row*FD;
    float acc = b0[c];
    #pragma unroll
    for (int f=0; f<FD; ++f) acc = fmaf(xr[f], w0[f*HD + c], acc);
    h[idx] = acc;
    unsigned short hi, lo; split_bf(acc, &hi, &lo);
    hhi[idx] = hi; hlo[idx] = lo;
}

// ---------------- weight transpose + hi/lo split: W[K][N] fp32 -> Wt[N][K] bf16 ----------------
__global__ __launch_bounds__(256) void k_cvt_wt(const float* __restrict__ W,
    unsigned short* __restrict__ Thi, unsigned short* __restrict__ Tlo, int N, int kbits)
{
    int idx = blockIdx.x*256 + threadIdx.x;      // over N*K, k fastest
    int K = 1 << kbits;
    int n = idx >> kbits, k = idx & (K-1);
    float v = W[(size_t)k*N + n];
    unsigned short hi, lo; split_bf(v, &hi, &lo);
    Thi[idx] = hi; Tlo[idx] = lo;
}

// ---------------- split-bf16 MFMA GEMM, 128x128 tile, 4 waves, 16x16x32 ----------------
// C = A(MxK) @ Wt(NxK)^T, acc fp32 via hi*hi + hi*lo + lo*hi.
// MODE 0 (in_proj, KDIM=512, N=1024): col<512 -> silu -> oA[row][512+col] (bf16 hi/lo)
//                                     col>=512 -> outF[row][col-512] fp32 (xi)
// MODE 1 (out_proj, KDIM=1024, N=512): outF = v + bias + resid (fp32, pre-LN)
template<int KDIM, int MODE>
__global__ __launch_bounds__(256) void k_mgemm(
    const unsigned short* __restrict__ Ahi, const unsigned short* __restrict__ Alo,
    const unsigned short* __restrict__ Bhi, const unsigned short* __restrict__ Blo,
    const float* __restrict__ bias, const float* __restrict__ resid,
    float* __restrict__ outF,
    unsigned short* __restrict__ oAhi, unsigned short* __restrict__ oAlo)
{
    __shared__ unsigned short lds[4 * 4096];     // 4 tiles of 128x32 bf16 (8 KB each)
    const int tid  = threadIdx.x;
    const int wv   = tid >> 6, lane = tid & 63;
    const int quad = lane >> 4, l16 = lane & 15;
    const size_t mBase = (size_t)blockIdx.y * 128;
    const int nBase = blockIdx.x * 128;
    const int wm = (wv & 1) * 64, wn = (wv >> 1) * 64;

    floatx4 acc[4][4] = {};

    const int rowIn = lane >> 2;                 // 0..15
    const int kofs  = (lane & 3) * 8;            // bf16 units within 32-wide k tile
    const unsigned short* gsrc[4];
    gsrc[0] = Ahi + mBase * KDIM;
    gsrc[1] = Alo + mBase * KDIM;
    gsrc[2] = Bhi + (size_t)nBase * KDIM;
    gsrc[3] = Blo + (size_t)nBase * KDIM;

    for (int k0 = 0; k0 < KDIM; k0 += 32) {
        #pragma unroll
        for (int b = 0; b < 4; ++b) {
            #pragma unroll
            for (int r = 0; r < 2; ++r) {
                int row = r * 64 + wv * 16 + rowIn;
                const unsigned short* g = gsrc[b] + (size_t)row * KDIM + k0 + kofs;
                unsigned short* l = &lds[b * 4096 + r * 2048 + wv * 512]; // +lane*16B implicit
                __builtin_amdgcn_global_load_lds(
                    (const __attribute__((address_space(1))) void*)g,
                    (__attribute__((address_space(3))) void*)l, 16, 0, 0);
            }
        }
        __syncthreads();
        bf16x8 ah[4], al[4], bh[4], bl[4];
        #pragma unroll
        for (int i = 0; i < 4; ++i) {
            int am = wm + 16*i + l16;
            ah[i] = *(const bf16x8*)&lds[0*4096 + am*32 + quad*8];
            al[i] = *(const bf16x8*)&lds[1*4096 + am*32 + quad*8];
            int bn = wn + 16*i + l16;
            bh[i] = *(const bf16x8*)&lds[2*4096 + bn*32 + quad*8];
            bl[i] = *(const bf16x8*)&lds[3*4096 + bn*32 + quad*8];
        }
        #pragma unroll
        for (int i = 0; i < 4; ++i)
            #pragma unroll
            for (int j = 0; j < 4; ++j) {
                acc[i][j] = __builtin_amdgcn_mfma_f32_16x16x32_bf16(ah[i], bh[j], acc[i][j], 0, 0, 0);
                acc[i][j] = __builtin_amdgcn_mfma_f32_16x16x32_bf16(ah[i], bl[j], acc[i][j], 0, 0, 0);
                acc[i][j] = __builtin_amdgcn_mfma_f32_16x16x32_bf16(al[i], bh[j], acc[i][j], 0, 0, 0);
            }
        __syncthreads();
    }

    // epilogue: D[row=(quad*4+r) within 16, col=l16 within 16]
    #pragma unroll
    for (int i = 0; i < 4; ++i) {
        #pragma unroll
        for (int r = 0; r < 4; ++r) {
            size_t row = mBase + wm + 16*i + quad*4 + r;
            #pragma unroll
            for (int j = 0; j < 4; ++j) {
                int col = nBase + wn + 16*j + l16;
                float v = acc[i][j][r] + bias[col];
                if (MODE == 0) {
                    if (col < 512) {
                        float s = silu_f(v);
                        unsigned short hi, lo; split_bf(s, &hi, &lo);
                        oAhi[row*1024 + 512 + col] = hi;
                        oAlo[row*1024 + 512 + col] = lo;
                    } else {
                        outF[row*512 + (col - 512)] = v;
                    }
                } else {
                    outF[row*512 + col] = v + resid[row*512 + col];
                }
            }
        }
    }
}

// ---------------- depthwise conv3 (pad 1) + bias + silu ----------------
__global__ __launch_bounds__(256) void k_conv(const float* __restrict__ xi,
    const float* __restrict__ cw, const float* __restrict__ cb,
    float* __restrict__ outc)
{
    int idx = blockIdx.x*256 + threadIdx.x;   // over rows*HD
    int c = idx & (HD-1);
    int l = (idx >> 9) & (LL-1);
    float xm = (l > 0)     ? xi[idx - HD] : 0.0f;
    float x0 = xi[idx];
    float xp = (l < LL-1)  ? xi[idx + HD] : 0.0f;
    float v = cb[c];
    v = fmaf(xm, cw[c*3+0], v);
    v = fmaf(x0, cw[c*3+1], v);
    v = fmaf(xp, cw[c*3+2], v);
    outc[idx] = silu_f(v);
}

// ---------------- dt bottleneck: v = xc * softplus((xc@xp_w+xp_b)@dt_w+dt_b) -> Abig cols 0..511 ----------------
__global__ __launch_bounds__(256) void k_dt(const float* __restrict__ xc,
    const float* __restrict__ xp_w, const float* __restrict__ xp_b,
    const float* __restrict__ dt_w, const float* __restrict__ dt_b,
    unsigned short* __restrict__ oAhi, unsigned short* __restrict__ oAlo)
{
    __shared__ float sj[4][16];
    __shared__ float tj[16];
    int row = blockIdx.x, tid = threadIdx.x;
    size_t base = (size_t)row * HD;
    float x0 = xc[base + tid];
    float x1 = xc[base + tid + 256];
    float tp[16];
    #pragma unroll
    for (int j = 0; j < 16; ++j)
        tp[j] = x0 * xp_w[tid*16 + j] + x1 * xp_w[(tid+256)*16 + j];
    #pragma unroll
    for (int j = 0; j < 16; ++j) {
        float v = tp[j];
        for (int off = 32; off; off >>= 1) v += __shfl_down(v, off);
        tp[j] = v;
    }
    int lane = tid & 63, wid = tid >> 6;
    if (lane == 0) {
        #pragma unroll
        for (int j = 0; j < 16; ++j) sj[wid][j] = tp[j];
    }
    __syncthreads();
    if (tid < 16) tj[tid] = sj[0][tid] + sj[1][tid] + sj[2][tid] + sj[3][tid] + xp_b[tid];
    __syncthreads();
    float d0 = dt_b[tid], d1 = dt_b[tid + 256];
    #pragma unroll
    for (int j = 0; j < 16; ++j) {
        float t = tj[j];
        d0 = fmaf(t, dt_w[j*HD + tid],       d0);
        d1 = fmaf(t, dt_w[j*HD + tid + 256], d1);
    }
    float v0 = x0 * softplus_f(d0);
    float v1 = x1 * softplus_f(d1);
    size_t ob = (size_t)row * 1024;
    unsigned short hi, lo;
    split_bf(v0, &hi, &lo); oAhi[ob + tid] = hi;       oAlo[ob + tid] = lo;
    split_bf(v1, &hi, &lo); oAhi[ob + tid + 256] = hi; oAlo[ob + tid + 256] = lo;
}

// ---------------- layernorm over last dim (512); emit fp32 + hi/lo bf16 ----------------
__global__ __launch_bounds__(256) void k_ln(const float* __restrict__ in,
    const float* __restrict__ g, const float* __restrict__ b,
    float* __restrict__ out, unsigned short* __restrict__ ohi, unsigned short* __restrict__ olo)
{
    __shared__ float s1[4], s2[4], sm[2];
    int row = blockIdx.x, tid = threadIdx.x;
    size_t base = (size_t)row * HD;
    float x0 = in[base + tid], x1 = in[base + tid + 256];
    float s = x0 + x1, q = x0*x0 + x1*x1;
    for (int off = 32; off; off >>= 1) { s += __shfl_down(s, off); q += __shfl_down(q, off); }
    int lane = tid & 63, wid = tid >> 6;
    if (!lane) { s1[wid] = s; s2[wid] = q; }
    __syncthreads();
    if (!tid) {
        float ts = s1[0]+s1[1]+s1[2]+s1[3];
        float tq = s2[0]+s2[1]+s2[2]+s2[3];
        float mu = ts / (float)HD;
        float var = tq / (float)HD - mu*mu;
        sm[0] = mu; sm[1] = rsqrtf(var + EPSV);
    }
    __syncthreads();
    float mu = sm[0], rs = sm[1];
    float o0 = (x0 - mu) * rs * g[tid]       + b[tid];
    float o1 = (x1 - mu) * rs * g[tid + 256] + b[tid + 256];
    out[base + tid]       = o0;
    out[base + tid + 256] = o1;
    unsigned short hi, lo;
    split_bf(o0, &hi, &lo); ohi[base + tid] = hi;       olo[base + tid] = lo;
    split_bf(o1, &hi, &lo); ohi[base + tid + 256] = hi; olo[base + tid + 256] = lo;
}

// ---------------- head: reg/dec, gate softmax+argmax, expert select ----------------
__global__ __launch_bounds__(256) void k_head(const float* __restrict__ h,
    const float* __restrict__ gumbel, const float* __restrict__ gate_w,
    const float* __restrict__ gate_b, const float* __restrict__ actor_w,
    const float* __restrict__ actor_b, const float* __restrict__ critic_w,
    const float* __restrict__ critic_b, float* __restrict__ out, int bofs)
{
    __shared__ float sred[4][4];
    __shared__ float sg;
    __shared__ int sestar;
    int bl = blockIdx.x, tid = threadIdx.x;
    int b = bofs + bl;                     // absolute batch index
    size_t base = (size_t)bl * LL * HD;
    float r0 = 0.f, r1 = 0.f;
    for (int l = 0; l < LL; ++l) {
        r0 += h[base + l*HD + tid];
        r1 += h[base + l*HD + tid + 256];
    }
    r0 *= (1.0f/LL); r1 *= (1.0f/LL);
    float dec0 = h[base + (LL-1)*HD + tid];
    float dec1 = h[base + (LL-1)*HD + tid + 256];

    float p[4];
    #pragma unroll
    for (int e = 0; e < 4; ++e)
        p[e] = r0 * gate_w[tid*4 + e] + r1 * gate_w[(tid+256)*4 + e];
    #pragma unroll
    for (int e = 0; e < 4; ++e) {
        float v = p[e];
        for (int off = 32; off; off >>= 1) v += __shfl_down(v, off);
        p[e] = v;
    }
    int lane = tid & 63, wid = tid >> 6;
    if (!lane) { for (int e = 0; e < 4; ++e) sred[wid][e] = p[e]; }
    __syncthreads();
    if (!tid) {
        float ge[4]; float mx = -1e30f;
        for (int e = 0; e < 4; ++e) {
            ge[e] = sred[0][e]+sred[1][e]+sred[2][e]+sred[3][e] + gate_b[e] + gumbel[b*4 + e];
            if (ge[e] > mx) mx = ge[e];
        }
        float ys[4], den = 0.f;
        for (int e = 0; e < 4; ++e) { ys[e] = expf(ge[e] - mx); den += ys[e]; }
        int estar = 0; float best = ge[0];
        for (int e = 1; e < 4; ++e) if (ge[e] > best) { best = ge[e]; estar = e; }
        float ye = ys[estar] / den;
        float gv = (1.0f + ye) - ye;          // exactly as reference: (hard + y) - y
        for (int e = 0; e < 4; ++e) out[2048 + b*4 + e] = (e == estar) ? gv : 0.0f;
        sg = gv; sestar = estar;
    }
    __syncthreads();
    float gv = sg; int estar = sestar;
    const float* aw  = actor_w  + (size_t)estar * HD * 3;
    const float* cwp = critic_w + (size_t)estar * HD;
    float q[4];
    #pragma unroll
    for (int a = 0; a < 3; ++a)
        q[a] = dec0 * aw[tid*3 + a] + dec1 * aw[(tid+256)*3 + a];
    q[3] = dec0 * cwp[tid] + dec1 * cwp[tid + 256];
    #pragma unroll
    for (int e = 0; e < 4; ++e) {
        float v = q[e];
        for (int off = 32; off; off >>= 1) v += __shfl_down(v, off);
        q[e] = v;
    }
    __syncthreads();
    if (!lane) { for (int e = 0; e < 4; ++e) sred[wid][e] = q[e]; }
    __syncthreads();
    if (!tid) {
        for (int a = 0; a < 3; ++a) {
            float v = sred[0][a]+sred[1][a]+sred[2][a]+sred[3][a];
            out[b*3 + a] = gv * (v + actor_b[estar*3 + a]);
        }
        float v = sred[0][3]+sred[1][3]+sred[2][3]+sred[3][3];
        out[1536 + b] = gv * (v + critic_b[estar]);
    }
}

extern "C" void kernel_launch(void* const* d_in, const int* in_sizes, int n_in,
                              void* d_out, int out_size, void* d_ws, size_t ws_size,
                              hipStream_t stream)
{
    const float* x        = (const float*)d_in[0];
    const float* gumbel   = (const float*)d_in[1];
    const float* w0       = (const float*)d_in[2];
    const float* b0       = (const float*)d_in[3];
    const float* ln_g     = (const float*)d_in[4];
    const float* ln_b     = (const float*)d_in[5];
    const float* gate_w   = (const float*)d_in[6];
    const float* gate_b   = (const float*)d_in[7];
    const float* actor_w  = (const float*)d_in[8];
    const float* actor_b  = (const float*)d_in[9];
    const float* critic_w = (const float*)d_in[10];
    const float* critic_b = (const float*)d_in[11];
    const float* in_w[2]   = {(const float*)d_in[12], (const float*)d_in[22]};
    const float* in_b[2]   = {(const float*)d_in[13], (const float*)d_in[23]};
    const float* conv_w[2] = {(const float*)d_in[14], (const float*)d_in[24]};
    const float* conv_b[2] = {(const float*)d_in[15], (const float*)d_in[25]};
    const float* xp_w[2]   = {(const float*)d_in[16], (const float*)d_in[26]};
    const float* xp_b[2]   = {(const float*)d_in[17], (const float*)d_in[27]};
    const float* dt_w[2]   = {(const float*)d_in[18], (const float*)d_in[28]};
    const float* dt_b[2]   = {(const float*)d_in[19], (const float*)d_in[29]};
    const float* out_w[2]  = {(const float*)d_in[20], (const float*)d_in[30]};
    const float* out_b[2]  = {(const float*)d_in[21], (const float*)d_in[31]};

    // Per-row scratch: h(2048) + xb(2048) + xc/hhi+hlo union(2048) + Abig_hi(2048) + Abig_lo(2048)
    // = 10240 B/row, plus 8 MB weight tail.
    int CB = 512;
    while (CB > 1 && (size_t)CB * LL * 10240 + (16u << 20) > ws_size) CB >>= 1;
    const int rows = CB * LL;
    const size_t CSZ = (size_t)rows * HD;        // floats per 512-wide buffer

    char* p = (char*)d_ws;
    float* h  = (float*)p;  p += CSZ * 4;
    float* xb = (float*)p;  p += CSZ * 4;
    float* xc = (float*)p;                       // union with {hhi, hlo}
    unsigned short* hhi = (unsigned short*)xc;
    unsigned short* hlo = hhi + CSZ;             p += CSZ * 4;
    unsigned short* Abig_hi = (unsigned short*)p; p += CSZ * 2 * 2;  // rows x 1024 bf16
    unsigned short* Abig_lo = (unsigned short*)p; p += CSZ * 2 * 2;
    unsigned short* wtb = (unsigned short*)p;
    unsigned short* iwh[2] = {wtb,            wtb + 4*524288};
    unsigned short* iwl[2] = {wtb +   524288, wtb + 5*524288};
    unsigned short* owh[2] = {wtb + 2*524288, wtb + 6*524288};
    unsigned short* owl[2] = {wtb + 3*524288, wtb + 7*524288};

    // weight transpose + split (cheap, every call)
    for (int m = 0; m < 2; ++m) {
        k_cvt_wt<<<2048, 256, 0, stream>>>(in_w[m],  iwh[m], iwl[m], 1024,  9); // K=512,N=1024
        k_cvt_wt<<<2048, 256, 0, stream>>>(out_w[m], owh[m], owl[m],  512, 10); // K=1024,N=512
    }

    const int nchunk = BB / CB;
    for (int c = 0; c < nchunk; ++c) {
        const float* xin = x + (size_t)c * CB * LL * FD;
        k_embed<<<rows*HD/256, 256, 0, stream>>>(xin, w0, b0, h, hhi, hlo);
        for (int m = 0; m < 2; ++m) {
            // in_proj: zi = h @ in_w + in_b ; z->silu->Abig[:,512:], xi->xb
            k_mgemm<512, 0><<<dim3(8, rows/128), 256, 0, stream>>>(
                hhi, hlo, iwh[m], iwl[m], in_b[m], nullptr, xb, Abig_hi, Abig_lo);
            // conv(xi) -> xc (overwrites hhi/hlo region; in_proj already consumed it)
            k_conv<<<rows*HD/256, 256, 0, stream>>>(xb, conv_w[m], conv_b[m], xc);
            // xi*dt -> Abig[:,0:512] (bf16 hi/lo)
            k_dt<<<rows, 256, 0, stream>>>(xc, xp_w[m], xp_b[m], dt_w[m], dt_b[m], Abig_hi, Abig_lo);
            // out_proj: Abig @ out_w + out_b + h -> xb (pre-LN fp32)
            k_mgemm<1024, 1><<<dim3(4, rows/128), 256, 0, stream>>>(
                Abig_hi, Abig_lo, owh[m], owl[m], out_b[m], h, xb, nullptr, nullptr);
            // LN -> h fp32 + hhi/hlo bf16 (A for next in_proj)
            k_ln<<<rows, 256, 0, stream>>>(xb, ln_g, ln_b, h, hhi, hlo);
        }
        k_head<<<CB, 256, 0, stream>>>(h, gumbel, gate_w, gate_b, actor_w, actor_b,
                                       critic_w, critic_b, (float*)d_out, c*CB);
    }
}